// Round 8
// baseline (651.058 us; speedup 1.0000x reference)
//
#include <hip/hip_runtime.h>

#define INDIM 256
#define HID 128
#define OUTD 64
#define BINSHIFT 8
#define MAXBIN 256   // supports M <= 65536

typedef _Float16 f16x8 __attribute__((ext_vector_type(8)));
typedef float    f32x4 __attribute__((ext_vector_type(4)));

// physical XCD id (HW_REG_XCC_ID = id 20, offset 0, width 32; HW-verified on MI355X)
__device__ __forceinline__ int xcc_id() {
    int x;
    asm("s_getreg_b32 %0, hwreg(20, 0, 32)" : "=s"(x));
    return x & 7;
}

// =============== pass 1: per-wg LDS histogram of dst>>8  (+ fused weight prep) ===============
__global__ __launch_bounds__(256) void k_hist_setup(const int* __restrict__ dst, int* __restrict__ bin_counts,
                                                    int E,
                                                    const float* __restrict__ W1, const float* __restrict__ W2,
                                                    _Float16* __restrict__ W1t, _Float16* __restrict__ W2t) {
    __shared__ int h[MAXBIN];
    int tid = threadIdx.x;
    h[tid] = 0;
    __syncthreads();
    int base = blockIdx.x * 4096;
#pragma unroll
    for (int i = 0; i < 16; i++) {
        int e = base + i * 256 + tid;
        if (e < E) atomicAdd(&h[dst[e] >> BINSHIFT], 1);
    }
    __syncthreads();
    int v = h[tid];
    if (v) atomicAdd(&bin_counts[tid], v);

    constexpr int NW1 = HID * INDIM;   // 32768
    constexpr int NW2 = OUTD * HID;    // 8192
    int id = blockIdx.x * 256 + tid;
    if (id < NW1) {
        int n = id / INDIM, k = id % INDIM;
        W1t[id] = (_Float16)W1[k * HID + n];
    } else if (id < NW1 + NW2) {
        int j = id - NW1;
        int n = j / HID, k = j % HID;
        W2t[j] = (_Float16)W2[k * OUTD + n];
    }
}

// =============== shared-memory shapes ===============
struct __align__(16) GemmSh { _Float16 As[128][40]; _Float16 Bs[128][40]; };  // 20 KiB
struct FillSh { int h[256]; int s[256]; int rb[256]; };
struct CsrSh  { int A[256]; int B[256]; int C[256]; };
union FillU { FillSh f; GemmSh g; };
union CsrU  { CsrSh  c; GemmSh g; };

// =============== MFMA fp16 GEMM body, BM=128 ===============
// OCW = output chunk width (halfs): output layout [BN/OCW][M][OCW] (chunk-major slices).
// fp32 input: row-major [M][K].  fp16 input: chunk-major [K/16][M][16] (h16c layout).
template <int BN, int K, typename AT, int OCW>
__device__ __forceinline__ void gemm_body(const AT* __restrict__ X, const _Float16* __restrict__ Wt,
                                          const float* __restrict__ dscale,   // nullptr -> unscaled
                                          _Float16* __restrict__ XW, int M, int rb,
                                          _Float16 (*As)[40], _Float16 (*Bs)[40])
{
    constexpr int NT = BN / 16;
    const int tid  = threadIdx.x;
    const int wave = tid >> 6;
    const int lane = tid & 63;
    const int m    = lane & 15;
    const int q    = lane >> 4;

    f32x4 acc[2][NT];
#pragma unroll
    for (int r = 0; r < 2; r++)
#pragma unroll
        for (int t = 0; t < NT; t++) acc[r][t] = (f32x4){0.f, 0.f, 0.f, 0.f};

    for (int kt = 0; kt < K; kt += 32) {
        if (kt) __syncthreads();
        if constexpr (sizeof(AT) == 4) {
#pragma unroll
            for (int i = 0; i < 4; i++) {            // 128 rows x 32 fp32, row-major source
                int ch = tid + i * 256;
                int row = ch >> 3, c4 = ch & 7, gr = rb + row;
                float4 v = make_float4(0.f, 0.f, 0.f, 0.f);
                if (gr < M) v = *(const float4*)((const float*)X + (long)gr * K + kt + c4 * 4);
                _Float16* p = &As[row][c4 * 4];
                p[0] = (_Float16)v.x; p[1] = (_Float16)v.y;
                p[2] = (_Float16)v.z; p[3] = (_Float16)v.w;
            }
        } else {
#pragma unroll
            for (int i = 0; i < 2; i++) {            // 128 rows x 32 fp16, chunk-major source [K/16][M][16]
                int ch = tid + i * 256;
                int row = ch >> 2, c8 = ch & 3, gr = rb + row;
                int f0 = kt + c8 * 8;                // multiple of 8
                uint4 v = make_uint4(0u, 0u, 0u, 0u);
                if (gr < M) v = *(const uint4*)((const _Float16*)X + ((long)(f0 >> 4) * M + gr) * 16 + (f0 & 8));
                *(uint4*)(&As[row][c8 * 8]) = v;
            }
        }
#pragma unroll
        for (int i = 0; i < BN / 64; i++) {          // BN rows x 32 fp16
            int ch = tid + i * 256;
            int n = ch >> 2, c8 = ch & 3;
            *(uint4*)(&Bs[n][c8 * 8]) = *(const uint4*)(Wt + (long)n * K + kt + c8 * 8);
        }
        __syncthreads();

        f16x8 a0 = *(const f16x8*)(&As[wave * 32 + m][q * 8]);
        f16x8 a1 = *(const f16x8*)(&As[wave * 32 + 16 + m][q * 8]);
#pragma unroll
        for (int t = 0; t < NT; t++) {
            f16x8 bf = *(const f16x8*)(&Bs[t * 16 + m][q * 8]);
            acc[0][t] = __builtin_amdgcn_mfma_f32_16x16x32_f16(a0, bf, acc[0][t], 0, 0, 0);
            acc[1][t] = __builtin_amdgcn_mfma_f32_16x16x32_f16(a1, bf, acc[1][t], 0, 0, 0);
        }
    }

#pragma unroll
    for (int r2 = 0; r2 < 2; r2++) {
        int row0 = rb + wave * 32 + r2 * 16 + q * 4;
#pragma unroll
        for (int rr = 0; rr < 4; rr++) {
            int row = row0 + rr;
            if (row < M) {
                float sc = dscale ? dscale[row] : 1.f;
#pragma unroll
                for (int t = 0; t < NT; t++) {
                    int col = t * 16 + m;
                    long addr = ((long)(col / OCW) * M + row) * OCW + (col % OCW);
                    XW[addr] = (_Float16)(acc[r2][t][rr] * sc);
                }
            }
        }
    }
}

// =============== binfill body ===============
__device__ __forceinline__ void fill_body(const int* __restrict__ src, const int* __restrict__ dst,
                                          const int* __restrict__ bin_counts, int* __restrict__ bin_cursor,
                                          int* __restrict__ binned, int E, FillSh& sh)
{
    int tid = threadIdx.x;
    sh.h[tid] = 0;
    int v = bin_counts[tid];     // zero beyond NBIN (memset)
    sh.s[tid] = v;
    __syncthreads();
    int base = blockIdx.x * 2048;
    int ep[8], eb[8], rk[8];
#pragma unroll
    for (int i = 0; i < 8; i++) {
        int e = base + i * 256 + tid;
        if (e < E) {
            int s = src[e], d = dst[e];
            ep[i] = (s << 8) | (d & 255);
            eb[i] = d >> BINSHIFT;
            rk[i] = atomicAdd(&sh.h[eb[i]], 1);
        } else {
            eb[i] = -1;
        }
    }
#pragma unroll
    for (int off = 1; off < 256; off <<= 1) {
        int t = (tid >= off) ? sh.s[tid - off] : 0;
        __syncthreads();
        sh.s[tid] += t;
        __syncthreads();
    }
    int c = sh.h[tid];
    if (c) sh.rb[tid] = (sh.s[tid] - v) + atomicAdd(&bin_cursor[tid], c);
    __syncthreads();
#pragma unroll
    for (int i = 0; i < 8; i++) {
        if (eb[i] >= 0) binned[sh.rb[eb[i]] + rk[i]] = ep[i];
    }
}

// =============== csr body: per-bin CSR finalize (row_start, dinv, edge_src) ===============
__device__ __forceinline__ void csr_body(const int* __restrict__ binned, const int* __restrict__ bin_counts,
                                         int* __restrict__ row_start, float* __restrict__ dinv,
                                         int* __restrict__ edge_src, int M, int E, CsrSh& sh)
{
    int b = blockIdx.x, tid = threadIdx.x;
    int v = bin_counts[tid];
    sh.A[tid] = v;
    __syncthreads();
#pragma unroll
    for (int off = 1; off < 256; off <<= 1) {
        int t = (tid >= off) ? sh.A[tid - off] : 0;
        __syncthreads();
        sh.A[tid] += t;
        __syncthreads();
    }
    sh.B[tid] = sh.A[tid] - v;   // exclusive
    __syncthreads();
    int beg = sh.B[b];
    int end = (b + 1 < 256) ? sh.B[b + 1] : E;
    if (b == 0 && tid == 0) row_start[M] = E;

    sh.A[tid] = 0;
    __syncthreads();
    for (int i = beg + tid; i < end; i += 256) {
        atomicAdd(&sh.A[binned[i] & 255], 1);
    }
    __syncthreads();
    int c = sh.A[tid];
    sh.B[tid] = c;
    __syncthreads();
#pragma unroll
    for (int off = 1; off < 256; off <<= 1) {
        int t = (tid >= off) ? sh.B[tid - off] : 0;
        __syncthreads();
        sh.B[tid] += t;
        __syncthreads();
    }
    int start = beg + sh.B[tid] - c;
    int node = (b << BINSHIFT) + tid;
    if (node < M) {
        row_start[node] = start;
        dinv[node] = rsqrtf(1.0f + (float)c);
    }
    sh.C[tid] = start;
    __syncthreads();
    for (int i = beg + tid; i < end; i += 256) {
        int p = binned[i];
        int pos = atomicAdd(&sh.C[p & 255], 1);
        edge_src[pos] = p >> 8;
    }
}

// =============== fused launches: build-pipeline blocks || layer-1 gemm blocks ===============
__global__ __launch_bounds__(256) void k_binfill_gemm(
    const int* __restrict__ src, const int* __restrict__ dst,
    const int* __restrict__ bin_counts, int* __restrict__ bin_cursor, int* __restrict__ binned, int E,
    const float* __restrict__ X, const _Float16* __restrict__ W1t, _Float16* __restrict__ XW, int M,
    int nfill, int rbofs)
{
    __shared__ FillU u;
    if ((int)blockIdx.x < nfill)
        fill_body(src, dst, bin_counts, bin_cursor, binned, E, u.f);
    else
        gemm_body<HID, INDIM, float, 16>(X, W1t, nullptr, XW, M, (rbofs + (int)blockIdx.x - nfill) * 128, u.g.As, u.g.Bs);
}

__global__ __launch_bounds__(256) void k_csr_gemm(
    const int* __restrict__ binned, const int* __restrict__ bin_counts,
    int* __restrict__ row_start, float* __restrict__ dinv, int* __restrict__ edge_src, int M, int E,
    const float* __restrict__ X, const _Float16* __restrict__ W1t, _Float16* __restrict__ XW,
    int nbin, int rbofs)
{
    __shared__ CsrU u;
    if ((int)blockIdx.x < nbin)
        csr_body(binned, bin_counts, row_start, dinv, edge_src, M, E, u.c);
    else
        gemm_body<HID, INDIM, float, 16>(X, W1t, nullptr, XW, M, (rbofs + (int)blockIdx.x - nbin) * 128, u.g.As, u.g.Bs);
}

// =============== standalone gemm (layer 2: h16c -> hw16c pre-scaled, both chunk-major) ===============
__global__ __launch_bounds__(256) void k_gemm2(const _Float16* __restrict__ X, const _Float16* __restrict__ Wt,
                                               const float* __restrict__ dscale,
                                               _Float16* __restrict__ XW, int M)
{
    __shared__ __align__(16) _Float16 As[128][40];
    __shared__ __align__(16) _Float16 Bs[OUTD][40];
    gemm_body<OUTD, HID, _Float16, 8>(X, Wt, dscale, XW, M, (int)blockIdx.x * 128, As, Bs);
}

// =============== layer-1 aggregation group body (chunk ch, nodes [g*128, g*128+128)) ===============
__device__ __forceinline__ void agg1_group(
    int ch, int g,
    const int* __restrict__ row_start, const int* __restrict__ edge_src,
    const _Float16* __restrict__ featc, const float* __restrict__ bias,
    const float* __restrict__ dinv, _Float16* __restrict__ h16c, int M)
{
    const int n = g * 128 + ((int)threadIdx.x >> 1);
    if (n >= M) return;
    const int q2 = threadIdx.x & 1;
    const _Float16* fb = featc + (long)ch * M * 16 + q2 * 8;   // + s*16 per node
    const int fo = ch * 16 + q2 * 8;

    float di = dinv[n];
    int beg = row_start[n], end = row_start[n + 1];
    f16x8 self = *(const f16x8*)(fb + (long)n * 16);
    float acc[8], acc2[8];
#pragma unroll
    for (int k = 0; k < 8; k++) { acc[k] = di * (float)self[k]; acc2[k] = 0.f; }

    int j = beg;
    for (; j + 7 < end; j += 8) {
        int s0 = edge_src[j],     s1 = edge_src[j + 1];
        int s2 = edge_src[j + 2], s3 = edge_src[j + 3];
        int s4 = edge_src[j + 4], s5 = edge_src[j + 5];
        int s6 = edge_src[j + 6], s7 = edge_src[j + 7];
        float d0 = dinv[s0], d1 = dinv[s1], d2 = dinv[s2], d3 = dinv[s3];
        float d4 = dinv[s4], d5 = dinv[s5], d6 = dinv[s6], d7 = dinv[s7];
        f16x8 v0 = *(const f16x8*)(fb + (long)s0 * 16);
        f16x8 v1 = *(const f16x8*)(fb + (long)s1 * 16);
        f16x8 v2 = *(const f16x8*)(fb + (long)s2 * 16);
        f16x8 v3 = *(const f16x8*)(fb + (long)s3 * 16);
        f16x8 v4 = *(const f16x8*)(fb + (long)s4 * 16);
        f16x8 v5 = *(const f16x8*)(fb + (long)s5 * 16);
        f16x8 v6 = *(const f16x8*)(fb + (long)s6 * 16);
        f16x8 v7 = *(const f16x8*)(fb + (long)s7 * 16);
#pragma unroll
        for (int k = 0; k < 8; k++) {
            acc[k]  = fmaf(d0, (float)v0[k], acc[k]);
            acc2[k] = fmaf(d1, (float)v1[k], acc2[k]);
            acc[k]  = fmaf(d2, (float)v2[k], acc[k]);
            acc2[k] = fmaf(d3, (float)v3[k], acc2[k]);
            acc[k]  = fmaf(d4, (float)v4[k], acc[k]);
            acc2[k] = fmaf(d5, (float)v5[k], acc2[k]);
            acc[k]  = fmaf(d6, (float)v6[k], acc[k]);
            acc2[k] = fmaf(d7, (float)v7[k], acc2[k]);
        }
    }
    for (; j + 3 < end; j += 4) {
        int s0 = edge_src[j],     s1 = edge_src[j + 1];
        int s2 = edge_src[j + 2], s3 = edge_src[j + 3];
        float d0 = dinv[s0], d1 = dinv[s1], d2 = dinv[s2], d3 = dinv[s3];
        f16x8 v0 = *(const f16x8*)(fb + (long)s0 * 16);
        f16x8 v1 = *(const f16x8*)(fb + (long)s1 * 16);
        f16x8 v2 = *(const f16x8*)(fb + (long)s2 * 16);
        f16x8 v3 = *(const f16x8*)(fb + (long)s3 * 16);
#pragma unroll
        for (int k = 0; k < 8; k++) {
            acc[k]  = fmaf(d0, (float)v0[k], acc[k]);
            acc2[k] = fmaf(d1, (float)v1[k], acc2[k]);
            acc[k]  = fmaf(d2, (float)v2[k], acc[k]);
            acc2[k] = fmaf(d3, (float)v3[k], acc2[k]);
        }
    }
    for (; j < end; j++) {
        int s = edge_src[j];
        float d = dinv[s];
        f16x8 v = *(const f16x8*)(fb + (long)s * 16);
#pragma unroll
        for (int k = 0; k < 8; k++) acc[k] = fmaf(d, (float)v[k], acc[k]);
    }

    f16x8 hh;
#pragma unroll
    for (int k = 0; k < 8; k++)
        hh[k] = (_Float16)tanhf(bias[fo + k] + di * (acc[k] + acc2[k]));
    *(f16x8*)(h16c + ((long)ch * M + n) * 16 + q2 * 8) = hh;
}

// =============== persistent layer-1 aggregation: XCD-pinned via HW_REG_XCC_ID + work-steal ===============
__global__ __launch_bounds__(256) void k_agg1_p(
    const int* __restrict__ row_start, const int* __restrict__ edge_src,
    const _Float16* __restrict__ featc, const float* __restrict__ bias,
    const float* __restrict__ dinv, _Float16* __restrict__ h16c,
    int* __restrict__ wq, int ngroups, int M)
{
    __shared__ int gsh;
    const int xcc = xcc_id();
#pragma unroll 1
    for (int p = 0; p < 8; p++) {
        const int ch = (xcc + p) & 7;
        while (true) {
            if (threadIdx.x == 0) gsh = atomicAdd(&wq[ch], 1);
            __syncthreads();
            int g = gsh;
            __syncthreads();
            if (g >= ngroups) break;
            agg1_group(ch, g, row_start, edge_src, featc, bias, dinv, h16c, M);
        }
    }
}

// =============== layer-2 aggregation group body (chunk ch, nodes [g*256, g*256+256)) ===============
__device__ __forceinline__ void agg2_group(
    int ch, int g,
    const int* __restrict__ row_start, const int* __restrict__ edge_src,
    const _Float16* __restrict__ featc, const float* __restrict__ bias,
    const float* __restrict__ dinv, float* __restrict__ out, int M)
{
    const int n = g * 256 + (int)threadIdx.x;
    if (n >= M) return;
    const _Float16* fb = featc + (long)ch * M * 8;
    const int fo = ch * 8;

    int beg = row_start[n], end = row_start[n + 1];
    f16x8 self = *(const f16x8*)(fb + (long)n * 8);
    float acc[8], acc2[8];
#pragma unroll
    for (int k = 0; k < 8; k++) { acc[k] = (float)self[k]; acc2[k] = 0.f; }

    int j = beg;
    for (; j + 7 < end; j += 8) {
        int s0 = edge_src[j],     s1 = edge_src[j + 1];
        int s2 = edge_src[j + 2], s3 = edge_src[j + 3];
        int s4 = edge_src[j + 4], s5 = edge_src[j + 5];
        int s6 = edge_src[j + 6], s7 = edge_src[j + 7];
        f16x8 v0 = *(const f16x8*)(fb + (long)s0 * 8);
        f16x8 v1 = *(const f16x8*)(fb + (long)s1 * 8);
        f16x8 v2 = *(const f16x8*)(fb + (long)s2 * 8);
        f16x8 v3 = *(const f16x8*)(fb + (long)s3 * 8);
        f16x8 v4 = *(const f16x8*)(fb + (long)s4 * 8);
        f16x8 v5 = *(const f16x8*)(fb + (long)s5 * 8);
        f16x8 v6 = *(const f16x8*)(fb + (long)s6 * 8);
        f16x8 v7 = *(const f16x8*)(fb + (long)s7 * 8);
#pragma unroll
        for (int k = 0; k < 8; k++) {
            acc[k]  += (float)v0[k] + (float)v1[k];
            acc2[k] += (float)v2[k] + (float)v3[k];
            acc[k]  += (float)v4[k] + (float)v5[k];
            acc2[k] += (float)v6[k] + (float)v7[k];
        }
    }
    for (; j + 3 < end; j += 4) {
        int s0 = edge_src[j],     s1 = edge_src[j + 1];
        int s2 = edge_src[j + 2], s3 = edge_src[j + 3];
        f16x8 v0 = *(const f16x8*)(fb + (long)s0 * 8);
        f16x8 v1 = *(const f16x8*)(fb + (long)s1 * 8);
        f16x8 v2 = *(const f16x8*)(fb + (long)s2 * 8);
        f16x8 v3 = *(const f16x8*)(fb + (long)s3 * 8);
#pragma unroll
        for (int k = 0; k < 8; k++) {
            acc[k]  += (float)v0[k] + (float)v1[k];
            acc2[k] += (float)v2[k] + (float)v3[k];
        }
    }
    for (; j < end; j++) {
        int s = edge_src[j];
        f16x8 v = *(const f16x8*)(fb + (long)s * 8);
#pragma unroll
        for (int k = 0; k < 8; k++) acc[k] += (float)v[k];
    }

    float di = dinv[n];
    float r[8];
#pragma unroll
    for (int k = 0; k < 8; k++) r[k] = bias[fo + k] + di * (acc[k] + acc2[k]);
    f32x4 o0 = {r[0], r[1], r[2], r[3]};
    f32x4 o1 = {r[4], r[5], r[6], r[7]};
    float* p = out + (long)n * OUTD + fo;
    __builtin_nontemporal_store(o0, (f32x4*)p);
    __builtin_nontemporal_store(o1, (f32x4*)(p + 4));
}

// =============== persistent layer-2 aggregation: XCD-pinned + work-steal ===============
__global__ __launch_bounds__(256) void k_agg2_p(
    const int* __restrict__ row_start, const int* __restrict__ edge_src,
    const _Float16* __restrict__ featc, const float* __restrict__ bias,
    const float* __restrict__ dinv, float* __restrict__ out,
    int* __restrict__ wq, int ngroups, int M)
{
    __shared__ int gsh;
    const int xcc = xcc_id();
#pragma unroll 1
    for (int p = 0; p < 8; p++) {
        const int ch = (xcc + p) & 7;
        while (true) {
            if (threadIdx.x == 0) gsh = atomicAdd(&wq[ch], 1);
            __syncthreads();
            int g = gsh;
            __syncthreads();
            if (g >= ngroups) break;
            agg2_group(ch, g, row_start, edge_src, featc, bias, dinv, out, M);
        }
    }
}

extern "C" void kernel_launch(void* const* d_in, const int* in_sizes, int n_in,
                              void* d_out, int out_size, void* d_ws, size_t ws_size,
                              hipStream_t stream) {
    const float* x  = (const float*)d_in[0];
    const int*   ei = (const int*)d_in[1];
    const float* W1 = (const float*)d_in[2];
    const float* b1 = (const float*)d_in[3];
    const float* W2 = (const float*)d_in[4];
    const float* b2 = (const float*)d_in[5];
    float* out = (float*)d_out;

    const int M = in_sizes[0] / INDIM;   // 50000
    const int E = in_sizes[1] / 2;       // 800000
    const int* srcp = ei;
    const int* dstp = ei + E;

    const int Mp   = (M + 63) & ~63;
    const int NBIN = (M + 255) >> BINSHIFT;  // 196

    // workspace layout (bin_cursor, bin_counts, work queues contiguous -> single memset)
    float*     dinv       = (float*)d_ws;
    int*       row_start  = (int*)(dinv + Mp);            // [M+1] <= Mp
    int*       bin_cursor = row_start + Mp;               // [MAXBIN]
    int*       bin_counts = bin_cursor + MAXBIN;          // [MAXBIN]
    int*       wq1        = bin_counts + MAXBIN;          // [8]
    int*       wq2        = wq1 + 8;                      // [8]
    _Float16*  W1t        = (_Float16*)(wq2 + 8);              // [HID][INDIM]
    _Float16*  W2t        = W1t + HID * INDIM;                 // [OUTD][HID]
    int*       binned     = (int*)(W2t + OUTD * HID);          // [E]
    int*       edge_src   = binned + E;                        // [E]
    _Float16*  xw16c      = (_Float16*)(edge_src + E);         // [8][M][16] unscaled, chunk-major
    _Float16*  h16c       = xw16c + (long)M * HID;             // [8][M][16] chunk-major
    _Float16*  hw16c      = h16c + (long)M * HID;              // [8][M][8]  pre-scaled, chunk-major

    const int NWH = (E + 4095) / 4096;   // hist wgs (>=160 needed for weight prep)
    const int NWF = (E + 2047) / 2048;   // binfill wgs
    const int GB  = (M + 127) / 128;     // gemm wgs (BM=128)
    const int GA  = GB / 3;              // gemm1 blocks riding with binfill
    const int GBc = GB - GA;             // gemm1 blocks riding with csr
    const int ngr1 = (M + 127) / 128;    // agg1 groups per chunk
    const int ngr2 = (M + 255) / 256;    // agg2 groups per chunk

    // ---- build + layer-1 gemm overlapped ----
    hipMemsetAsync(bin_cursor, 0, (2 * MAXBIN + 16) * sizeof(int), stream);
    k_hist_setup<<<NWH, 256, 0, stream>>>(dstp, bin_counts, E, W1, W2, W1t, W2t);
    k_binfill_gemm<<<NWF + GA, 256, 0, stream>>>(srcp, dstp, bin_counts, bin_cursor, binned, E,
                                                 x, W1t, xw16c, M, NWF, 0);
    k_csr_gemm<<<NBIN + GBc, 256, 0, stream>>>(binned, bin_counts, row_start, dinv, edge_src, M, E,
                                               x, W1t, xw16c, NBIN, GA);

    // ---- layer 1 aggregation: persistent, physically XCD-pinned chunk slices ----
    k_agg1_p<<<2048, 256, 0, stream>>>(row_start, edge_src, xw16c, b1, dinv, h16c, wq1, ngr1, M);

    // ---- layer 2 gemm: hw16c = fp16(dinv * (h @ W2)), chunk-major in and out ----
    k_gemm2<<<GB, 256, 0, stream>>>(h16c, W2t, dinv, hw16c, M);

    // ---- layer 2 aggregation: persistent, physically XCD-pinned chunk slices ----
    k_agg2_p<<<2048, 256, 0, stream>>>(row_start, edge_src, hw16c, b2, dinv, out, wq2, ngr2, M);
}

// Round 9
// 220.704 us; speedup vs baseline: 2.9499x; 2.9499x over previous
//
#include <hip/hip_runtime.h>

#define INDIM 256
#define HID 128
#define OUTD 64
#define BINSHIFT 8
#define MAXBIN 256   // supports M <= 65536

typedef _Float16 f16x8 __attribute__((ext_vector_type(8)));
typedef float    f32x4 __attribute__((ext_vector_type(4)));

// =============== pass 1: per-wg LDS histogram of dst>>8  (+ fused weight prep) ===============
__global__ __launch_bounds__(256) void k_hist_setup(const int* __restrict__ dst, int* __restrict__ bin_counts,
                                                    int E,
                                                    const float* __restrict__ W1, const float* __restrict__ W2,
                                                    _Float16* __restrict__ W1t, _Float16* __restrict__ W2t) {
    __shared__ int h[MAXBIN];
    int tid = threadIdx.x;
    h[tid] = 0;
    __syncthreads();
    int base = blockIdx.x * 4096;
#pragma unroll
    for (int i = 0; i < 16; i++) {
        int e = base + i * 256 + tid;
        if (e < E) atomicAdd(&h[dst[e] >> BINSHIFT], 1);
    }
    __syncthreads();
    int v = h[tid];
    if (v) atomicAdd(&bin_counts[tid], v);

    // fused weight transpose/convert (independent of histogram)
    constexpr int NW1 = HID * INDIM;   // 32768
    constexpr int NW2 = OUTD * HID;    // 8192
    int id = blockIdx.x * 256 + tid;
    if (id < NW1) {
        int n = id / INDIM, k = id % INDIM;
        W1t[id] = (_Float16)W1[k * HID + n];
    } else if (id < NW1 + NW2) {
        int j = id - NW1;
        int n = j / HID, k = j % HID;
        W2t[j] = (_Float16)W2[k * OUTD + n];
    }
}

// =============== shared-memory shapes (unions let build blocks + gemm blocks share one kernel) ===============
struct __align__(16) GemmSh { _Float16 As[128][40]; _Float16 Bs[128][40]; };  // 20 KiB, 80B row stride (16B mult)
struct FillSh { int h[256]; int s[256]; int rb[256]; };
struct CsrSh  { int A[256]; int B[256]; int C[256]; };
union FillU { FillSh f; GemmSh g; };
union CsrU  { CsrSh  c; GemmSh g; };

// =============== MFMA fp16 GEMM body, BM=128, unscaled fp16 output (row-major) ===============
// X[M][K] (fp32 or fp16), Wt[BN][K] fp16. XW[row] = fp16((X@W)[row]).  dinv applied later in agg.
template <int BN, int K, typename AT>
__device__ __forceinline__ void gemm_body(const AT* __restrict__ X, const _Float16* __restrict__ Wt,
                                          _Float16* __restrict__ XW, int M, int rb,
                                          _Float16 (*As)[40], _Float16 (*Bs)[40])
{
    constexpr int NT = BN / 16;
    const int tid  = threadIdx.x;
    const int wave = tid >> 6;
    const int lane = tid & 63;
    const int m    = lane & 15;
    const int q    = lane >> 4;

    f32x4 acc[2][NT];
#pragma unroll
    for (int r = 0; r < 2; r++)
#pragma unroll
        for (int t = 0; t < NT; t++) acc[r][t] = (f32x4){0.f, 0.f, 0.f, 0.f};

    for (int kt = 0; kt < K; kt += 32) {
        if (kt) __syncthreads();
        if constexpr (sizeof(AT) == 4) {
#pragma unroll
            for (int i = 0; i < 4; i++) {            // 128 rows x 32 fp32
                int ch = tid + i * 256;
                int row = ch >> 3, c4 = ch & 7, gr = rb + row;
                float4 v = make_float4(0.f, 0.f, 0.f, 0.f);
                if (gr < M) v = *(const float4*)((const float*)X + (long)gr * K + kt + c4 * 4);
                _Float16* p = &As[row][c4 * 4];
                p[0] = (_Float16)v.x; p[1] = (_Float16)v.y;
                p[2] = (_Float16)v.z; p[3] = (_Float16)v.w;
            }
        } else {
#pragma unroll
            for (int i = 0; i < 2; i++) {            // 128 rows x 32 fp16
                int ch = tid + i * 256;
                int row = ch >> 2, c8 = ch & 3, gr = rb + row;
                uint4 v = make_uint4(0u, 0u, 0u, 0u);
                if (gr < M) v = *(const uint4*)((const _Float16*)X + (long)gr * K + kt + c8 * 8);
                *(uint4*)(&As[row][c8 * 8]) = v;
            }
        }
#pragma unroll
        for (int i = 0; i < BN / 64; i++) {          // BN rows x 32 fp16
            int ch = tid + i * 256;
            int n = ch >> 2, c8 = ch & 3;
            *(uint4*)(&Bs[n][c8 * 8]) = *(const uint4*)(Wt + (long)n * K + kt + c8 * 8);
        }
        __syncthreads();

        f16x8 a0 = *(const f16x8*)(&As[wave * 32 + m][q * 8]);
        f16x8 a1 = *(const f16x8*)(&As[wave * 32 + 16 + m][q * 8]);
#pragma unroll
        for (int t = 0; t < NT; t++) {
            f16x8 bf = *(const f16x8*)(&Bs[t * 16 + m][q * 8]);
            acc[0][t] = __builtin_amdgcn_mfma_f32_16x16x32_f16(a0, bf, acc[0][t], 0, 0, 0);
            acc[1][t] = __builtin_amdgcn_mfma_f32_16x16x32_f16(a1, bf, acc[1][t], 0, 0, 0);
        }
    }

#pragma unroll
    for (int r2 = 0; r2 < 2; r2++) {
        int row0 = rb + wave * 32 + r2 * 16 + q * 4;
#pragma unroll
        for (int rr = 0; rr < 4; rr++) {
            int row = row0 + rr;
            if (row < M) {
#pragma unroll
                for (int t = 0; t < NT; t++)
                    XW[(long)row * BN + t * 16 + m] = (_Float16)acc[r2][t][rr];
            }
        }
    }
}

// =============== binfill body: scatter packed (src<<8 | dst&255) into bin runs ===============
// Self-derives the exclusive bin scan from global bin_counts (kills the k_bscan launch).
__device__ __forceinline__ void fill_body(const int* __restrict__ src, const int* __restrict__ dst,
                                          const int* __restrict__ bin_counts, int* __restrict__ bin_cursor,
                                          int* __restrict__ binned, int E, FillSh& sh)
{
    int tid = threadIdx.x;
    sh.h[tid] = 0;
    int v = bin_counts[tid];     // zero beyond NBIN (memset)
    sh.s[tid] = v;
    __syncthreads();
    int base = blockIdx.x * 2048;
    int ep[8], eb[8], rk[8];
#pragma unroll
    for (int i = 0; i < 8; i++) {
        int e = base + i * 256 + tid;
        if (e < E) {
            int s = src[e], d = dst[e];
            ep[i] = (s << 8) | (d & 255);
            eb[i] = d >> BINSHIFT;
            rk[i] = atomicAdd(&sh.h[eb[i]], 1);
        } else {
            eb[i] = -1;
        }
    }
    // inclusive scan of global bin counts (syncs also order the h[] atomics above)
#pragma unroll
    for (int off = 1; off < 256; off <<= 1) {
        int t = (tid >= off) ? sh.s[tid - off] : 0;
        __syncthreads();
        sh.s[tid] += t;
        __syncthreads();
    }
    int c = sh.h[tid];
    if (c) sh.rb[tid] = (sh.s[tid] - v) + atomicAdd(&bin_cursor[tid], c);  // global excl + relative cursor
    __syncthreads();
#pragma unroll
    for (int i = 0; i < 8; i++) {
        if (eb[i] >= 0) binned[sh.rb[eb[i]] + rk[i]] = ep[i];
    }
}

// =============== csr body: per-bin CSR finalize (row_start, dinv, edge_src) ===============
__device__ __forceinline__ void csr_body(const int* __restrict__ binned, const int* __restrict__ bin_counts,
                                         int* __restrict__ row_start, float* __restrict__ dinv,
                                         int* __restrict__ edge_src, int M, int E, CsrSh& sh)
{
    int b = blockIdx.x, tid = threadIdx.x;
    // bin-offset scan (replaces global bin_start array)
    int v = bin_counts[tid];
    sh.A[tid] = v;
    __syncthreads();
#pragma unroll
    for (int off = 1; off < 256; off <<= 1) {
        int t = (tid >= off) ? sh.A[tid - off] : 0;
        __syncthreads();
        sh.A[tid] += t;
        __syncthreads();
    }
    sh.B[tid] = sh.A[tid] - v;   // exclusive
    __syncthreads();
    int beg = sh.B[b];
    int end = (b + 1 < 256) ? sh.B[b + 1] : E;   // excl[b+1] == incl[b]
    if (b == 0 && tid == 0) row_start[M] = E;

    sh.A[tid] = 0;
    __syncthreads();             // also fences all reads of sh.B above
    for (int i = beg + tid; i < end; i += 256) {
        atomicAdd(&sh.A[binned[i] & 255], 1);
    }
    __syncthreads();
    int c = sh.A[tid];
    sh.B[tid] = c;
    __syncthreads();
#pragma unroll
    for (int off = 1; off < 256; off <<= 1) {
        int t = (tid >= off) ? sh.B[tid - off] : 0;
        __syncthreads();
        sh.B[tid] += t;
        __syncthreads();
    }
    int start = beg + sh.B[tid] - c;
    int node = (b << BINSHIFT) + tid;
    if (node < M) {
        row_start[node] = start;
        dinv[node] = rsqrtf(1.0f + (float)c);
    }
    sh.C[tid] = start;
    __syncthreads();
    for (int i = beg + tid; i < end; i += 256) {
        int p = binned[i];
        int pos = atomicAdd(&sh.C[p & 255], 1);
        edge_src[pos] = p >> 8;
    }
}

// =============== fused launches: build-pipeline blocks || layer-1 gemm blocks ===============
__global__ __launch_bounds__(256) void k_binfill_gemm(
    const int* __restrict__ src, const int* __restrict__ dst,
    const int* __restrict__ bin_counts, int* __restrict__ bin_cursor, int* __restrict__ binned, int E,
    const float* __restrict__ X, const _Float16* __restrict__ W1t, _Float16* __restrict__ XW, int M,
    int nfill, int rbofs)
{
    __shared__ FillU u;
    if ((int)blockIdx.x < nfill)
        fill_body(src, dst, bin_counts, bin_cursor, binned, E, u.f);
    else
        gemm_body<HID, INDIM, float>(X, W1t, XW, M, (rbofs + (int)blockIdx.x - nfill) * 128, u.g.As, u.g.Bs);
}

__global__ __launch_bounds__(256) void k_csr_gemm(
    const int* __restrict__ binned, const int* __restrict__ bin_counts,
    int* __restrict__ row_start, float* __restrict__ dinv, int* __restrict__ edge_src, int M, int E,
    const float* __restrict__ X, const _Float16* __restrict__ W1t, _Float16* __restrict__ XW,
    int nbin, int rbofs)
{
    __shared__ CsrU u;
    if ((int)blockIdx.x < nbin)
        csr_body(binned, bin_counts, row_start, dinv, edge_src, M, E, u.c);
    else
        gemm_body<HID, INDIM, float>(X, W1t, XW, M, (rbofs + (int)blockIdx.x - nbin) * 128, u.g.As, u.g.Bs);
}

// =============== standalone gemm (layer 2) ===============
template <int BN, int K, typename AT>
__global__ __launch_bounds__(256) void k_gemm_mfma(const AT* __restrict__ X, const _Float16* __restrict__ Wt,
                                                   _Float16* __restrict__ XW, int M)
{
    __shared__ __align__(16) _Float16 As[128][40];
    __shared__ __align__(16) _Float16 Bs[BN][40];
    gemm_body<BN, K, AT>(X, Wt, XW, M, (int)blockIdx.x * 128, As, Bs);
}

// =============== CSR gather-aggregation (unscaled fp16 table, dinv[src] fused as fmac) ===============
// out[n] = act(bias + dinv[n] * (dinv[n]*feat[n] + sum_{e in(n)} dinv[src_e]*feat[src_e]))
template <int F, bool TANH, typename OutT>
__global__ __launch_bounds__(256) void k_agg_csr(const int* __restrict__ row_start,
                                                 const int* __restrict__ edge_src,
                                                 const _Float16* __restrict__ feat,
                                                 const float* __restrict__ bias,
                                                 const float* __restrict__ dinv,
                                                 OutT* __restrict__ out, int M) {
    constexpr int LPN = F / 8;          // lanes per node, 8 halfs (16B) each
    constexpr int NPB = 256 / LPN;
    int n = blockIdx.x * NPB + threadIdx.x / LPN;
    int c = threadIdx.x % LPN;
    if (n >= M) return;
    int beg = row_start[n], end = row_start[n + 1];
    float di = dinv[n];

    f16x8 self = *(const f16x8*)(feat + (long)n * F + c * 8);
    float acc[8], acc2[8];
#pragma unroll
    for (int k = 0; k < 8; k++) { acc[k] = di * (float)self[k]; acc2[k] = 0.f; }

    int j = beg;
    for (; j + 7 < end; j += 8) {
        int s0 = edge_src[j],     s1 = edge_src[j + 1];
        int s2 = edge_src[j + 2], s3 = edge_src[j + 3];
        int s4 = edge_src[j + 4], s5 = edge_src[j + 5];
        int s6 = edge_src[j + 6], s7 = edge_src[j + 7];
        float d0 = dinv[s0], d1 = dinv[s1], d2 = dinv[s2], d3 = dinv[s3];
        float d4 = dinv[s4], d5 = dinv[s5], d6 = dinv[s6], d7 = dinv[s7];
        f16x8 v0 = *(const f16x8*)(feat + (long)s0 * F + c * 8);
        f16x8 v1 = *(const f16x8*)(feat + (long)s1 * F + c * 8);
        f16x8 v2 = *(const f16x8*)(feat + (long)s2 * F + c * 8);
        f16x8 v3 = *(const f16x8*)(feat + (long)s3 * F + c * 8);
        f16x8 v4 = *(const f16x8*)(feat + (long)s4 * F + c * 8);
        f16x8 v5 = *(const f16x8*)(feat + (long)s5 * F + c * 8);
        f16x8 v6 = *(const f16x8*)(feat + (long)s6 * F + c * 8);
        f16x8 v7 = *(const f16x8*)(feat + (long)s7 * F + c * 8);
#pragma unroll
        for (int k = 0; k < 8; k++) {
            acc[k]  = fmaf(d0, (float)v0[k], acc[k]);
            acc2[k] = fmaf(d1, (float)v1[k], acc2[k]);
            acc[k]  = fmaf(d2, (float)v2[k], acc[k]);
            acc2[k] = fmaf(d3, (float)v3[k], acc2[k]);
            acc[k]  = fmaf(d4, (float)v4[k], acc[k]);
            acc2[k] = fmaf(d5, (float)v5[k], acc2[k]);
            acc[k]  = fmaf(d6, (float)v6[k], acc[k]);
            acc2[k] = fmaf(d7, (float)v7[k], acc2[k]);
        }
    }
    for (; j + 3 < end; j += 4) {
        int s0 = edge_src[j],     s1 = edge_src[j + 1];
        int s2 = edge_src[j + 2], s3 = edge_src[j + 3];
        float d0 = dinv[s0], d1 = dinv[s1], d2 = dinv[s2], d3 = dinv[s3];
        f16x8 v0 = *(const f16x8*)(feat + (long)s0 * F + c * 8);
        f16x8 v1 = *(const f16x8*)(feat + (long)s1 * F + c * 8);
        f16x8 v2 = *(const f16x8*)(feat + (long)s2 * F + c * 8);
        f16x8 v3 = *(const f16x8*)(feat + (long)s3 * F + c * 8);
#pragma unroll
        for (int k = 0; k < 8; k++) {
            acc[k]  = fmaf(d0, (float)v0[k], acc[k]);
            acc2[k] = fmaf(d1, (float)v1[k], acc2[k]);
            acc[k]  = fmaf(d2, (float)v2[k], acc[k]);
            acc2[k] = fmaf(d3, (float)v3[k], acc2[k]);
        }
    }
    for (; j < end; j++) {
        int s = edge_src[j];
        float d = dinv[s];
        f16x8 v = *(const f16x8*)(feat + (long)s * F + c * 8);
#pragma unroll
        for (int k = 0; k < 8; k++) acc[k] = fmaf(d, (float)v[k], acc[k]);
    }

    float r[8];
#pragma unroll
    for (int k = 0; k < 8; k++) r[k] = bias[c * 8 + k] + di * (acc[k] + acc2[k]);
    if (TANH) {
#pragma unroll
        for (int k = 0; k < 8; k++) r[k] = tanhf(r[k]);
    }
    if constexpr (sizeof(OutT) == 2) {
        f16x8 o;
#pragma unroll
        for (int k = 0; k < 8; k++) o[k] = (_Float16)r[k];
        __builtin_nontemporal_store(o, (f16x8*)((_Float16*)out + (long)n * F + c * 8));
    } else {
        f32x4 o0 = {r[0], r[1], r[2], r[3]};
        f32x4 o1 = {r[4], r[5], r[6], r[7]};
        float* p = (float*)out + (long)n * F + c * 8;
        __builtin_nontemporal_store(o0, (f32x4*)p);
        __builtin_nontemporal_store(o1, (f32x4*)(p + 4));
    }
}

extern "C" void kernel_launch(void* const* d_in, const int* in_sizes, int n_in,
                              void* d_out, int out_size, void* d_ws, size_t ws_size,
                              hipStream_t stream) {
    const float* x  = (const float*)d_in[0];
    const int*   ei = (const int*)d_in[1];
    const float* W1 = (const float*)d_in[2];
    const float* b1 = (const float*)d_in[3];
    const float* W2 = (const float*)d_in[4];
    const float* b2 = (const float*)d_in[5];
    float* out = (float*)d_out;

    const int M = in_sizes[0] / INDIM;   // 50000
    const int E = in_sizes[1] / 2;       // 800000
    const int* srcp = ei;
    const int* dstp = ei + E;

    const int Mp   = (M + 63) & ~63;
    const int NBIN = (M + 255) >> BINSHIFT;  // 196

    // workspace layout
    float*     dinv       = (float*)d_ws;
    int*       row_start  = (int*)(dinv + Mp);            // [M+1] <= Mp
    int*       bin_cursor = row_start + Mp;               // [MAXBIN]
    int*       bin_counts = bin_cursor + MAXBIN;          // [MAXBIN]
    _Float16*  W1t        = (_Float16*)(bin_counts + MAXBIN);  // [HID][INDIM]
    _Float16*  W2t        = W1t + HID * INDIM;                 // [OUTD][HID]
    int*       binned     = (int*)(W2t + OUTD * HID);          // [E] packed src<<8|dstlow
    int*       edge_src   = binned + E;                        // [E]
    _Float16*  xw16       = (_Float16*)(edge_src + E);         // [M][HID] unscaled
    _Float16*  h16        = xw16 + (long)M * HID;              // [M][HID]
    _Float16*  hw16       = xw16;                              // alias: xw dead after agg1

    const int NWH = (E + 4095) / 4096;   // hist wgs (>=160 needed for weight prep)
    const int NWF = (E + 2047) / 2048;   // binfill wgs
    const int GB  = (M + 127) / 128;     // layer-1/2 gemm wgs (BM=128)
    const int GA  = GB / 3;              // gemm1 blocks riding with binfill
    const int GBc = GB - GA;             // gemm1 blocks riding with csr

    // ---- build + layer-1 gemm overlapped ----
    hipMemsetAsync(bin_cursor, 0, 2 * MAXBIN * sizeof(int), stream);
    k_hist_setup<<<NWH, 256, 0, stream>>>(dstp, bin_counts, E, W1, W2, W1t, W2t);
    k_binfill_gemm<<<NWF + GA, 256, 0, stream>>>(srcp, dstp, bin_counts, bin_cursor, binned, E,
                                                 x, W1t, xw16, M, NWF, 0);
    k_csr_gemm<<<NBIN + GBc, 256, 0, stream>>>(binned, bin_counts, row_start, dinv, edge_src, M, E,
                                               x, W1t, xw16, NBIN, GA);

    // ---- layer 1 aggregation: h = tanh(b1 + dinv*(dinv*xw + sum dinv[s]*xw[s])) ----
    k_agg_csr<HID, true, _Float16><<<(M + 15) / 16, 256, 0, stream>>>(row_start, edge_src, xw16, b1, dinv, h16, M);

    // ---- layer 2: hw16 = fp16(h@W2) ; out = b2 + dinv*(dinv*self + edges) ----
    k_gemm_mfma<OUTD, HID, _Float16><<<GB, 256, 0, stream>>>(h16, W2t, hw16, M);
    k_agg_csr<OUTD, false, float><<<(M + 31) / 32, 256, 0, stream>>>(row_start, edge_src, hw16, b2, dinv, out, M);
}